// Round 13
// baseline (178.962 us; speedup 1.0000x reference)
//
#include <hip/hip_runtime.h>
#include <hip/hip_bf16.h>

#define NN 32768      // nodes
#define NE 131072     // edges
#define HH 4          // heads

constexpr float kLrelu = 0.2f;

using bf16x8 = __attribute__((ext_vector_type(8))) __bf16;
using f32x4  = __attribute__((ext_vector_type(4))) float;

__device__ inline short f2b(float f) {
    __hip_bfloat16 h = __float2bfloat16(f);          // RTNE
    return __builtin_bit_cast(short, h);
}
__device__ inline float b2f(short s) {
    __hip_bfloat16 h = __builtin_bit_cast(__hip_bfloat16, s);
    return __bfloat162float(h);
}
__device__ inline float blo(int u) {                 // bf16 in bits[15:0]
    return __builtin_bit_cast(float, (int)(u << 16));
}
__device__ inline float bhi(int u) {                 // bf16 in bits[31:16]
    return __builtin_bit_cast(float, (int)(u & 0xffff0000));
}
__device__ inline float lrexp(float x) {             // exp(leaky_relu(x))
    return __expf(x > 0.f ? x : kLrelu * x);
}

// ---------------------------------------------------------------------------
// LDS-staged bf16 MFMA GEMM body (round-9-proven), device function so two
// shapes share one launch (block-uniform dispatch on blockIdx.z).
// ---------------------------------------------------------------------------
template<int K, int LDA, int OUTN, int BM, int BN, bool BF16OUT>
__device__ __forceinline__ void gemm_dev(
    const short* __restrict__ A, const short* __restrict__ Wt,
    const float* __restrict__ bias,
    float* __restrict__ Cf, short* __restrict__ Cb,
    short* lds, int bx, int by)
{
    constexpr int KP    = K + 8;
    constexpr int WM    = BM / 32;
    constexpr int WN    = 4 / WM;
    constexpr int WBN   = BN / WN;
    constexpr int CF    = WBN / 16;
    constexpr int CPR   = K / 8;
    constexpr int TOT   = (BM + BN) * KP;
    constexpr int SLICE = TOT / 4;

    short* As = lds;
    short* Bs = lds + BM * KP;

    const int tid  = threadIdx.x;
    const int wave = tid >> 6;
    const int lane = tid & 63;
    const int lr   = lane & 15;
    const int kb   = lane >> 4;
    const int wm   = wave % WM;
    const int wn   = wave / WM;
    const int row0 = bx * BM;
    const int col0 = by * BN;

    #pragma unroll
    for (int g = tid; g < BM * CPR; g += 256) {
        int r = g / CPR, c = g - r * CPR;
        bf16x8 v = *(const bf16x8*)(A + (size_t)(row0 + r) * LDA + c * 8);
        *(bf16x8*)(As + r * KP + c * 8) = v;
    }
    #pragma unroll
    for (int g = tid; g < BN * CPR; g += 256) {
        int r = g / CPR, c = g - r * CPR;
        bf16x8 v = *(const bf16x8*)(Wt + (size_t)(col0 + r) * K + c * 8);
        *(bf16x8*)(Bs + r * KP + c * 8) = v;
    }
    __syncthreads();

    f32x4 acc[2][CF] = {};
    #pragma unroll
    for (int k0 = 0; k0 < K; k0 += 32) {
        bf16x8 af0 = *(const bf16x8*)(As + (wm * 32 + lr     ) * KP + k0 + kb * 8);
        bf16x8 af1 = *(const bf16x8*)(As + (wm * 32 + lr + 16) * KP + k0 + kb * 8);
        #pragma unroll
        for (int cf = 0; cf < CF; ++cf) {
            bf16x8 bv = *(const bf16x8*)(Bs + (wn * WBN + cf * 16 + lr) * KP + k0 + kb * 8);
            acc[0][cf] = __builtin_amdgcn_mfma_f32_16x16x32_bf16(af0, bv, acc[0][cf], 0, 0, 0);
            acc[1][cf] = __builtin_amdgcn_mfma_f32_16x16x32_bf16(af1, bv, acc[1][cf], 0, 0, 0);
        }
    }

    #pragma unroll
    for (int mf = 0; mf < 2; ++mf) {
        __syncthreads();
        if constexpr (BF16OUT) {
            constexpr int LEP = WBN + 8;
            short* ep = lds + wave * SLICE;
            #pragma unroll
            for (int cf = 0; cf < CF; ++cf) {
                const int c  = cf * 16 + lr;
                const float bv = bias ? bias[col0 + wn * WBN + c] : 0.0f;
                #pragma unroll
                for (int j = 0; j < 4; ++j)
                    ep[(kb * 4 + j) * LEP + c] = f2b(acc[mf][cf][j] + bv);
            }
            __syncthreads();
            constexpr int CROW = WBN / 8;
            for (int g = lane; g < 16 * CROW; g += 64) {
                int r = g / CROW, cc = g - r * CROW;
                bf16x8 v = *(const bf16x8*)(ep + r * LEP + cc * 8);
                *(bf16x8*)(Cb + (size_t)(row0 + wm * 32 + mf * 16 + r) * OUTN
                              + col0 + wn * WBN + cc * 8) = v;
            }
        } else {
            constexpr int LEPF = WBN + 4;
            float* epf = (float*)(lds + wave * SLICE);
            #pragma unroll
            for (int cf = 0; cf < CF; ++cf) {
                const int c  = cf * 16 + lr;
                const float bv = bias ? bias[col0 + wn * WBN + c] : 0.0f;
                #pragma unroll
                for (int j = 0; j < 4; ++j)
                    epf[(kb * 4 + j) * LEPF + c] = acc[mf][cf][j] + bv;
            }
            __syncthreads();
            constexpr int CROWF = WBN / 4;
            for (int g = lane; g < 16 * CROWF; g += 64) {
                int r = g / CROWF, cc = g - r * CROWF;
                float4 v = *(const float4*)(epf + r * LEPF + cc * 4);
                *(float4*)(Cf + (size_t)(row0 + wm * 32 + mf * 16 + r) * OUTN
                              + col0 + wn * WBN + cc * 4) = v;
            }
        }
    }
}

// ---------------------------------------------------------------------------
// Two independent GEMMs in one launch; blockIdx.z selects shape.
// ---------------------------------------------------------------------------
template<int K1, int LDA1, int OUTN1, int BM1, int BN1, bool BO1,
         int K2, int LDA2, int OUTN2, int BM2, int BN2, bool BO2>
__global__ __launch_bounds__(256) void dual_gemm(
    const short* A1, const short* Wt1, const float* b1, float* Cf1, short* Cb1,
    int nbx1, int nby1,
    const short* A2, const short* Wt2, const float* b2, float* Cf2, short* Cb2,
    int nbx2, int nby2)
{
    constexpr int TOT1 = (BM1 + BN1) * (K1 + 8);
    constexpr int TOT2 = (BM2 + BN2) * (K2 + 8);
    constexpr int TOT  = TOT1 > TOT2 ? TOT1 : TOT2;
    __shared__ short lds[TOT];
    if (blockIdx.z == 0) {
        if ((int)blockIdx.x < nbx1 && (int)blockIdx.y < nby1)
            gemm_dev<K1, LDA1, OUTN1, BM1, BN1, BO1>(A1, Wt1, b1, Cf1, Cb1, lds,
                                                     blockIdx.x, blockIdx.y);
    } else {
        if ((int)blockIdx.x < nbx2 && (int)blockIdx.y < nby2)
            gemm_dev<K2, LDA2, OUTN2, BM2, BN2, BO2>(A2, Wt2, b2, Cf2, Cb2, lds,
                                                     blockIdx.x, blockIdx.y);
    }
}

// ---------------------------------------------------------------------------
// Merged node scores for BOTH paths in one launch (grid split).
// ---------------------------------------------------------------------------
template<int F>
__device__ inline void score_one(
    const short* __restrict__ proj_b,
    const float* __restrict__ a_src, const float* __restrict__ a_trg,
    float* __restrict__ ssrc, float* __restrict__ strg, int t)
{
    int n = t >> 2, h = t & 3;
    const int4* p = (const int4*)(proj_b + (size_t)n * (4 * F) + h * F);
    const float* as = a_src + h * F;
    const float* at = a_trg + h * F;
    float ss = 0.f, st = 0.f;
    #pragma unroll
    for (int c = 0; c < F / 8; ++c) {
        int4 v = p[c];
        int u[4] = { v.x, v.y, v.z, v.w };
        #pragma unroll
        for (int q = 0; q < 4; ++q) {
            float x0 = blo(u[q]), x1 = bhi(u[q]);
            ss += x0 * as[c * 8 + 2 * q] + x1 * as[c * 8 + 2 * q + 1];
            st += x0 * at[c * 8 + 2 * q] + x1 * at[c * 8 + 2 * q + 1];
        }
    }
    ssrc[t] = ss;
    strg[t] = st;
}

__global__ __launch_bounds__(256) void scores_both(
    const short* __restrict__ projG,
    const float* __restrict__ agsG, const float* __restrict__ agtG,
    float* __restrict__ ssrcG, float* __restrict__ strgG,
    const short* __restrict__ projC,
    const float* __restrict__ acsC, const float* __restrict__ actC,
    float* __restrict__ ssrcC, float* __restrict__ strgC)
{
    int t = blockIdx.x * 256 + threadIdx.x;
    if (t < NN * HH) score_one<64>(projG, agsG, agtG, ssrcG, strgG, t);
    else             score_one<96>(projC, acsC, actC, ssrcC, strgC, t - NN * HH);
}

// ---------------------------------------------------------------------------
// Fused prologue: concat (0..5119), 6 weight transposes (5120..5983),
// zero deg arrays (5984..6047).
// ---------------------------------------------------------------------------
__global__ __launch_bounds__(256) void prep_kernel(
    const float* __restrict__ rna, const float* __restrict__ prot,
    short* __restrict__ cb,
    const float* W0, const float* W1, const float* W2,
    const float* W3, const float* W4, const float* W5,
    short* T0, short* T1, short* T2, short* T3, short* T4, short* T5,
    int4* __restrict__ zero_p)
{
    const int bid = blockIdx.x;
    if (bid < 5120) {
        int t = bid * 256 + threadIdx.x;
        int n = t / 40, j = (t - n * 40) * 4;
        float4 v = (j < 128) ? *(const float4*)(rna  + (size_t)n * 128 + j)
                             : *(const float4*)(prot + (size_t)n * 32 + (j - 128));
        short4 o = { f2b(v.x), f2b(v.y), f2b(v.z), f2b(v.w) };
        *(short4*)(cb + (size_t)n * 160 + j) = o;
    } else if (bid < 5984) {
        int idx = bid - 5120;
        int wsel = idx / 144, sub = idx - wsel * 144;
        int K, N; const float* W; short* T;
        switch (wsel) {
            case 0: K = 128; N =  64; W = W0; T = T0; break;
            case 1: K =  64; N = 256; W = W1; T = T1; break;
            case 2: K =  64; N = 128; W = W2; T = T2; break;
            case 3: K = 160; N =  96; W = W3; T = T3; break;
            case 4: K =  96; N = 384; W = W4; T = T4; break;
            default:K =  96; N = 160; W = W5; T = T5; break;
        }
        int t = sub * 256 + threadIdx.x;
        if (t >= K * N) return;
        int n = t / K, k = t - n * K;
        T[t] = f2b(W[(size_t)k * N + n]);
    } else {
        zero_p[(bid - 5984) * 256 + threadIdx.x] = make_int4(0, 0, 0, 0);
    }
}

// ---------------------------------------------------------------------------
// Dual CSR build (trg-CSR for aggregation, src-CSR for cross denominators).
// ---------------------------------------------------------------------------
__global__ __launch_bounds__(256) void hist_dual(const int* __restrict__ ei,
                                                 int* __restrict__ deg_t,
                                                 int* __restrict__ deg_s)
{
    int e = blockIdx.x * 256 + threadIdx.x;
    if (e >= NE) return;
    atomicAdd(&deg_s[ei[e]], 1);
    atomicAdd(&deg_t[ei[NE + e]], 1);
}

__global__ __launch_bounds__(1024) void scan_dual(
    const int* __restrict__ deg_t, int* __restrict__ rowptr_t, int* __restrict__ cursor_t,
    const int* __restrict__ deg_s, int* __restrict__ rowptr_s, int* __restrict__ cursor_s)
{
    const int* deg    = blockIdx.x ? deg_s    : deg_t;
    int*       rowptr = blockIdx.x ? rowptr_s : rowptr_t;
    int*       cursor = blockIdx.x ? cursor_s : cursor_t;
    __shared__ int sums[1024];
    const int t = threadIdx.x;
    const int base = t * 32;
    int local[32];
    int s = 0;
    #pragma unroll
    for (int i = 0; i < 32; ++i) { local[i] = s; s += deg[base + i]; }
    sums[t] = s;
    __syncthreads();
    for (int off = 1; off < 1024; off <<= 1) {
        int v = (t >= off) ? sums[t - off] : 0;
        __syncthreads();
        sums[t] += v;
        __syncthreads();
    }
    const int prev = (t == 0) ? 0 : sums[t - 1];
    #pragma unroll
    for (int i = 0; i < 32; ++i) {
        rowptr[base + i] = prev + local[i];
        cursor[base + i] = prev + local[i];
    }
    if (t == 1023) rowptr[NN] = prev + s;
}

__global__ __launch_bounds__(256) void scatter_dual(
    const int* __restrict__ ei,
    int* __restrict__ cursor_t, int* __restrict__ csr_srcT,
    int* __restrict__ cursor_s, int* __restrict__ csr_trgS)
{
    int e = blockIdx.x * 256 + threadIdx.x;
    if (e >= NE) return;
    int s = ei[e], t = ei[NE + e];
    int st = atomicAdd(&cursor_t[t], 1);
    csr_srcT[st] = s;
    int ss = atomicAdd(&cursor_s[s], 1);
    csr_trgS[ss] = t;
}

// ---------------------------------------------------------------------------
// Cross denominator reciprocals via src-CSR.
// ---------------------------------------------------------------------------
__global__ __launch_bounds__(256) void den_src_kernel(
    const int* __restrict__ rowptr_s, const int* __restrict__ csr_trgS,
    const float* __restrict__ ssrc, const float* __restrict__ strg,
    float* __restrict__ recip)
{
    int n = blockIdx.x * 256 + threadIdx.x;
    if (n >= NN) return;
    const int beg = rowptr_s[n], end = rowptr_s[n + 1];
    const float4 sv = *(const float4*)(ssrc + 4 * (size_t)n);
    float d0 = 0.f, d1 = 0.f, d2 = 0.f, d3 = 0.f;
    for (int sl = beg; sl < end; ++sl) {
        const int t = csr_trgS[sl];
        const float4 tv = *(const float4*)(strg + 4 * (size_t)t);
        d0 += lrexp(sv.x + tv.x); d1 += lrexp(sv.y + tv.y);
        d2 += lrexp(sv.z + tv.z); d3 += lrexp(sv.w + tv.w);
    }
    *(float4*)(recip + 4 * (size_t)n) =
        make_float4(1.f / (d0 + 1e-16f), 1.f / (d1 + 1e-16f),
                    1.f / (d2 + 1e-16f), 1.f / (d3 + 1e-16f));
}

// ---------------------------------------------------------------------------
// BOTH aggregates, one launch, EDGE-SPLIT (2 halves per node -> serial chain
// halved, 2x in-flight gathers). Block-granular path dispatch.
// GAT blocks: 6 nodes x (32 f-lanes x 2 halves) -> one node per 64-lane wave
// (zero intra-wave degree divergence); halves combined via __shfl_xor(.,32).
// Cross blocks: 4 nodes x (48 f-lanes x 2 halves); halves combined via LDS.
// ---------------------------------------------------------------------------
#define GAT_BLKS 5462   // ceil(32768/6)
__global__ __launch_bounds__(384) void aggregate_mega(
    const int* __restrict__ rowptr_t, const int* __restrict__ csr_srcT,
    const float* __restrict__ ssrcG, const float* __restrict__ strgG,
    const float* __restrict__ ssrcC, const float* __restrict__ strgC,
    const float* __restrict__ recip,
    const short* __restrict__ projG, const short* __restrict__ projC,
    const short* __restrict__ xG, const short* __restrict__ xC,
    const float* __restrict__ biasG, const float* __restrict__ biasC,
    short* __restrict__ aggG, short* __restrict__ aggC)
{
    __shared__ float red[2][192];          // cross half-combine (4 nodes x 48)
    const int bid = blockIdx.x;
    const int tid = threadIdx.x;

    if (bid < GAT_BLKS) {
        const int node = bid * 6 + (tid >> 6);
        if (node >= NN) return;            // whole wave exits together
        const int lane = tid & 63;
        const int half = lane >> 5;        // 0/1
        const int f2   = (lane & 31) * 2;
        const int beg  = rowptr_t[node], end = rowptr_t[node + 1];
        const float4 stv = *(const float4*)(strgG + 4 * (size_t)node);

        float h0l = 0.f, h1l = 0.f, h2l = 0.f, h3l = 0.f;
        float h0h = 0.f, h1h = 0.f, h2h = 0.f, h3h = 0.f;
        float d0 = 0.f, d1 = 0.f, d2 = 0.f, d3 = 0.f;

        for (int sl = beg + half; sl < end; sl += 2) {
            const int s = csr_srcT[sl];
            const float4 sv = *(const float4*)(ssrcG + 4 * (size_t)s);
            const float e0 = lrexp(sv.x + stv.x);
            const float e1 = lrexp(sv.y + stv.y);
            const float e2 = lrexp(sv.z + stv.z);
            const float e3 = lrexp(sv.w + stv.w);
            const short* p = projG + (size_t)s * 256 + f2;
            const int u0 = *(const int*)(p);
            const int u1 = *(const int*)(p + 64);
            const int u2 = *(const int*)(p + 128);
            const int u3 = *(const int*)(p + 192);
            d0 += e0; d1 += e1; d2 += e2; d3 += e3;
            h0l += e0 * blo(u0); h0h += e0 * bhi(u0);
            h1l += e1 * blo(u1); h1h += e1 * bhi(u1);
            h2l += e2 * blo(u2); h2h += e2 * bhi(u2);
            h3l += e3 * blo(u3); h3h += e3 * bhi(u3);
        }
        // combine halves (register-only, lanes l <-> l^32)
        d0 += __shfl_xor(d0, 32); d1 += __shfl_xor(d1, 32);
        d2 += __shfl_xor(d2, 32); d3 += __shfl_xor(d3, 32);
        h0l += __shfl_xor(h0l, 32); h0h += __shfl_xor(h0h, 32);
        h1l += __shfl_xor(h1l, 32); h1h += __shfl_xor(h1h, 32);
        h2l += __shfl_xor(h2l, 32); h2h += __shfl_xor(h2h, 32);
        h3l += __shfl_xor(h3l, 32); h3h += __shfl_xor(h3h, 32);
        if (half == 0) {
            const float r0 = 1.f / (d0 + 1e-16f), r1 = 1.f / (d1 + 1e-16f);
            const float r2 = 1.f / (d2 + 1e-16f), r3 = 1.f / (d3 + 1e-16f);
            const float a0 = h0l * r0 + h1l * r1 + h2l * r2 + h3l * r3;
            const float a1 = h0h * r0 + h1h * r1 + h2h * r2 + h3h * r3;
            const int o = node * 64 + f2;
            const int ux = *(const int*)(xG + o);
            const float v0 = a0 * 0.25f + blo(ux) + biasG[f2];
            const float v1 = a1 * 0.25f + bhi(ux) + biasG[f2 + 1];
            *(int*)(aggG + o) = (f2b(v0) & 0xffff) | ((int)f2b(v1) << 16);
        }
    } else {
        const int b    = bid - GAT_BLKS;
        const int nl   = tid / 96;         // 0..3
        const int r    = tid - nl * 96;
        const int half = r / 48;           // 0/1
        const int f2   = (r - half * 48) * 2;
        const int node = b * 4 + nl;
        const int beg  = rowptr_t[node], end = rowptr_t[node + 1];
        const float4 stv = *(const float4*)(strgC + 4 * (size_t)node);

        float a0 = 0.f, a1 = 0.f;
        for (int sl = beg + half; sl < end; sl += 2) {
            const int s = csr_srcT[sl];
            const float4 sv = *(const float4*)(ssrcC + 4 * (size_t)s);
            const float4 rc = *(const float4*)(recip + 4 * (size_t)s);
            const float e0 = lrexp(sv.x + stv.x) * rc.x;
            const float e1 = lrexp(sv.y + stv.y) * rc.y;
            const float e2 = lrexp(sv.z + stv.z) * rc.z;
            const float e3 = lrexp(sv.w + stv.w) * rc.w;
            const short* p = projC + (size_t)s * 384 + f2;
            const int u0 = *(const int*)(p);
            const int u1 = *(const int*)(p + 96);
            const int u2 = *(const int*)(p + 192);
            const int u3 = *(const int*)(p + 288);
            a0 += e0 * blo(u0) + e1 * blo(u1) + e2 * blo(u2) + e3 * blo(u3);
            a1 += e0 * bhi(u0) + e1 * bhi(u1) + e2 * bhi(u2) + e3 * bhi(u3);
        }
        const int slot = nl * 48 + (f2 >> 1);
        if (half == 1) { red[0][slot] = a0; red[1][slot] = a1; }
        __syncthreads();
        if (half == 0) {
            a0 += red[0][slot];
            a1 += red[1][slot];
            const int o = node * 96 + f2;
            const int ux = *(const int*)(xC + o);
            const float v0 = a0 * 0.25f + blo(ux) + biasC[f2];
            const float v1 = a1 * 0.25f + bhi(ux) + biasC[f2 + 1];
            *(int*)(aggC + o) = (f2b(v0) & 0xffff) | ((int)f2b(v1) << 16);
        }
    }
}

// ---------------------------------------------------------------------------
extern "C" void kernel_launch(void* const* d_in, const int* in_sizes, int n_in,
                              void* d_out, int out_size, void* d_ws, size_t ws_size,
                              hipStream_t stream)
{
    const float* rna   = (const float*)d_in[0];    // [N,128]
    const float* prot  = (const float*)d_in[1];    // [N,32]
    const int*   ei    = (const int*)  d_in[2];    // [2,E]
    const float* Wgp   = (const float*)d_in[3];    // [128,64]
    const float* bgp   = (const float*)d_in[4];
    const float* Wgr   = (const float*)d_in[5];    // [64,128]
    const float* bgr   = (const float*)d_in[6];
    const float* Wg    = (const float*)d_in[7];    // [64,256]
    const float* ags   = (const float*)d_in[8];    // [4,64]
    const float* agt   = (const float*)d_in[9];
    const float* bg    = (const float*)d_in[10];   // [64]
    const float* Wcp   = (const float*)d_in[11];   // [160,96]
    const float* bcp   = (const float*)d_in[12];
    const float* Wcr   = (const float*)d_in[13];   // [96,160]
    const float* bcr   = (const float*)d_in[14];
    const float* Wc    = (const float*)d_in[15];   // [96,384]
    const float* acs   = (const float*)d_in[16];   // [4,96]
    const float* act   = (const float*)d_in[17];
    const float* bc    = (const float*)d_in[18];   // [96]

    float* out_gat   = (float*)d_out;              // [N,128]
    float* out_cross = out_gat + (size_t)NN * 128; // [N,160]

    // ---- workspace layout (~79 MB) ----
    float* ssrcG  = (float*)d_ws;                  // N*4
    float* strgG  = ssrcG + (size_t)NN * 4;        // N*4
    float* ssrcC  = strgG + (size_t)NN * 4;        // N*4
    float* strgC  = ssrcC + (size_t)NN * 4;        // N*4
    float* recip  = strgC + (size_t)NN * 4;        // N*4
    short* projG  = (short*)(recip + (size_t)NN * 4); // N*256 bf16
    short* projC  = projG + (size_t)NN * 256;      // N*384 bf16
    short* cb     = projC + (size_t)NN * 384;      // N*160 bf16
    short* x_pG   = cb    + (size_t)NN * 160;      // N*64 bf16
    short* x_pC   = x_pG  + (size_t)NN * 64;       // N*96 bf16
    short* aggG   = x_pC  + (size_t)NN * 96;       // N*64 bf16
    short* aggC   = aggG  + (size_t)NN * 64;       // N*96 bf16
    short* wt_gp  = aggC  + (size_t)NN * 96;       // [64,128]
    short* wt_g   = wt_gp + 128 * 64;              // [256,64]
    short* wt_gr  = wt_g  + 64 * 256;              // [128,64]
    short* wt_cp  = wt_gr + 64 * 128;              // [96,160]
    short* wt_c   = wt_cp + 160 * 96;              // [384,96]
    short* wt_cr  = wt_c  + 96 * 384;              // [160,96]
    int*   deg_t  = (int*)(wt_cr + 96 * 160);      // N
    int*   deg_s  = deg_t  + NN;                   // N
    int*   cursor_t = deg_s  + NN;                 // N
    int*   cursor_s = cursor_t + NN;               // N
    int*   rowptr_t = cursor_s + NN;               // N+1
    int*   rowptr_s = rowptr_t + NN + 1;           // N+1
    int*   csr_srcT = rowptr_s + NN + 1;           // E
    int*   csr_trgS = csr_srcT + NE;               // E

    // ---- prologue + CSR build ----
    prep_kernel<<<6048, 256, 0, stream>>>(rna, prot, cb,
                                          Wgp, Wg, Wgr, Wcp, Wc, Wcr,
                                          wt_gp, wt_g, wt_gr, wt_cp, wt_c, wt_cr,
                                          (int4*)deg_t);
    hist_dual<<<NE / 256, 256, 0, stream>>>(ei, deg_t, deg_s);
    scan_dual<<<2, 1024, 0, stream>>>(deg_t, rowptr_t, cursor_t, deg_s, rowptr_s, cursor_s);
    scatter_dual<<<NE / 256, 256, 0, stream>>>(ei, cursor_t, csr_srcT, cursor_s, csr_trgS);

    // ---- stage-1 projection GEMMs (both paths, one launch) ----
    dual_gemm<128, 160,  64, 32,  64, true,
              160, 160,  96, 64,  96, true><<<dim3(1024, 1, 2), 256, 0, stream>>>(
        cb, wt_gp, bgp, nullptr, x_pG, 1024, 1,
        cb, wt_cp, bcp, nullptr, x_pC,  512, 1);

    // ---- stage-2 projection GEMMs (both paths, one launch) ----
    dual_gemm< 64,  64, 256, 64, 128, true,
               96,  96, 384, 64, 128, true><<<dim3(512, 3, 2), 256, 0, stream>>>(
        x_pG, wt_g, nullptr, nullptr, projG, 512, 2,
        x_pC, wt_c, nullptr, nullptr, projC, 512, 3);

    // ---- scores (merged), cross denominators ----
    scores_both<<<(2 * NN * HH) / 256, 256, 0, stream>>>(
        projG, ags, agt, ssrcG, strgG, projC, acs, act, ssrcC, strgC);
    den_src_kernel<<<NN / 256, 256, 0, stream>>>(rowptr_s, csr_trgS, ssrcC, strgC, recip);

    // ---- both aggregates, one launch (edge-split, block-granular) ----
    aggregate_mega<<<GAT_BLKS + NN / 4, 384, 0, stream>>>(
        rowptr_t, csr_srcT, ssrcG, strgG, ssrcC, strgC, recip,
        projG, projC, x_pG, x_pC, bg, bc, aggG, aggC);

    // ---- reprojection GEMMs (both paths, one launch) ----
    dual_gemm< 64,  64, 128, 64,  64, false,
               96,  96, 160, 64, 160, false><<<dim3(512, 2, 2), 256, 0, stream>>>(
        aggG, wt_gr, bgr, out_gat,   nullptr, 512, 2,
        aggC, wt_cr, bcr, out_cross, nullptr, 512, 1);
}

// Round 14
// 166.881 us; speedup vs baseline: 1.0724x; 1.0724x over previous
//
#include <hip/hip_runtime.h>
#include <hip/hip_bf16.h>

#define NN 32768      // nodes
#define NE 131072     // edges
#define HH 4          // heads

constexpr float kLrelu = 0.2f;

using bf16x8 = __attribute__((ext_vector_type(8))) __bf16;
using f32x4  = __attribute__((ext_vector_type(4))) float;

__device__ inline short f2b(float f) {
    __hip_bfloat16 h = __float2bfloat16(f);          // RTNE
    return __builtin_bit_cast(short, h);
}
__device__ inline float b2f(short s) {
    __hip_bfloat16 h = __builtin_bit_cast(__hip_bfloat16, s);
    return __bfloat162float(h);
}
__device__ inline float blo(int u) {                 // bf16 in bits[15:0]
    return __builtin_bit_cast(float, (int)(u << 16));
}
__device__ inline float bhi(int u) {                 // bf16 in bits[31:16]
    return __builtin_bit_cast(float, (int)(u & 0xffff0000));
}
__device__ inline float lrexp(float x) {             // exp(leaky_relu(x))
    return __expf(x > 0.f ? x : kLrelu * x);
}

// ---------------------------------------------------------------------------
// LDS-staged bf16 MFMA GEMM body (round-9-proven), device function so two
// shapes share one launch (block-uniform dispatch on blockIdx.z).
// ---------------------------------------------------------------------------
template<int K, int LDA, int OUTN, int BM, int BN, bool BF16OUT>
__device__ __forceinline__ void gemm_dev(
    const short* __restrict__ A, const short* __restrict__ Wt,
    const float* __restrict__ bias,
    float* __restrict__ Cf, short* __restrict__ Cb,
    short* lds, int bx, int by)
{
    constexpr int KP    = K + 8;
    constexpr int WM    = BM / 32;
    constexpr int WN    = 4 / WM;
    constexpr int WBN   = BN / WN;
    constexpr int CF    = WBN / 16;
    constexpr int CPR   = K / 8;
    constexpr int TOT   = (BM + BN) * KP;
    constexpr int SLICE = TOT / 4;

    short* As = lds;
    short* Bs = lds + BM * KP;

    const int tid  = threadIdx.x;
    const int wave = tid >> 6;
    const int lane = tid & 63;
    const int lr   = lane & 15;
    const int kb   = lane >> 4;
    const int wm   = wave % WM;
    const int wn   = wave / WM;
    const int row0 = bx * BM;
    const int col0 = by * BN;

    #pragma unroll
    for (int g = tid; g < BM * CPR; g += 256) {
        int r = g / CPR, c = g - r * CPR;
        bf16x8 v = *(const bf16x8*)(A + (size_t)(row0 + r) * LDA + c * 8);
        *(bf16x8*)(As + r * KP + c * 8) = v;
    }
    #pragma unroll
    for (int g = tid; g < BN * CPR; g += 256) {
        int r = g / CPR, c = g - r * CPR;
        bf16x8 v = *(const bf16x8*)(Wt + (size_t)(col0 + r) * K + c * 8);
        *(bf16x8*)(Bs + r * KP + c * 8) = v;
    }
    __syncthreads();

    f32x4 acc[2][CF] = {};
    #pragma unroll
    for (int k0 = 0; k0 < K; k0 += 32) {
        bf16x8 af0 = *(const bf16x8*)(As + (wm * 32 + lr     ) * KP + k0 + kb * 8);
        bf16x8 af1 = *(const bf16x8*)(As + (wm * 32 + lr + 16) * KP + k0 + kb * 8);
        #pragma unroll
        for (int cf = 0; cf < CF; ++cf) {
            bf16x8 bv = *(const bf16x8*)(Bs + (wn * WBN + cf * 16 + lr) * KP + k0 + kb * 8);
            acc[0][cf] = __builtin_amdgcn_mfma_f32_16x16x32_bf16(af0, bv, acc[0][cf], 0, 0, 0);
            acc[1][cf] = __builtin_amdgcn_mfma_f32_16x16x32_bf16(af1, bv, acc[1][cf], 0, 0, 0);
        }
    }

    #pragma unroll
    for (int mf = 0; mf < 2; ++mf) {
        __syncthreads();
        if constexpr (BF16OUT) {
            constexpr int LEP = WBN + 8;
            short* ep = lds + wave * SLICE;
            #pragma unroll
            for (int cf = 0; cf < CF; ++cf) {
                const int c  = cf * 16 + lr;
                const float bv = bias ? bias[col0 + wn * WBN + c] : 0.0f;
                #pragma unroll
                for (int j = 0; j < 4; ++j)
                    ep[(kb * 4 + j) * LEP + c] = f2b(acc[mf][cf][j] + bv);
            }
            __syncthreads();
            constexpr int CROW = WBN / 8;
            for (int g = lane; g < 16 * CROW; g += 64) {
                int r = g / CROW, cc = g - r * CROW;
                bf16x8 v = *(const bf16x8*)(ep + r * LEP + cc * 8);
                *(bf16x8*)(Cb + (size_t)(row0 + wm * 32 + mf * 16 + r) * OUTN
                              + col0 + wn * WBN + cc * 8) = v;
            }
        } else {
            constexpr int LEPF = WBN + 4;
            float* epf = (float*)(lds + wave * SLICE);
            #pragma unroll
            for (int cf = 0; cf < CF; ++cf) {
                const int c  = cf * 16 + lr;
                const float bv = bias ? bias[col0 + wn * WBN + c] : 0.0f;
                #pragma unroll
                for (int j = 0; j < 4; ++j)
                    epf[(kb * 4 + j) * LEPF + c] = acc[mf][cf][j] + bv;
            }
            __syncthreads();
            constexpr int CROWF = WBN / 4;
            for (int g = lane; g < 16 * CROWF; g += 64) {
                int r = g / CROWF, cc = g - r * CROWF;
                float4 v = *(const float4*)(epf + r * LEPF + cc * 4);
                *(float4*)(Cf + (size_t)(row0 + wm * 32 + mf * 16 + r) * OUTN
                              + col0 + wn * WBN + cc * 4) = v;
            }
        }
    }
}

// ---------------------------------------------------------------------------
// Two independent GEMMs in one launch; blockIdx.z selects shape.
// ---------------------------------------------------------------------------
template<int K1, int LDA1, int OUTN1, int BM1, int BN1, bool BO1,
         int K2, int LDA2, int OUTN2, int BM2, int BN2, bool BO2>
__global__ __launch_bounds__(256) void dual_gemm(
    const short* A1, const short* Wt1, const float* b1, float* Cf1, short* Cb1,
    int nbx1, int nby1,
    const short* A2, const short* Wt2, const float* b2, float* Cf2, short* Cb2,
    int nbx2, int nby2)
{
    constexpr int TOT1 = (BM1 + BN1) * (K1 + 8);
    constexpr int TOT2 = (BM2 + BN2) * (K2 + 8);
    constexpr int TOT  = TOT1 > TOT2 ? TOT1 : TOT2;
    __shared__ short lds[TOT];
    if (blockIdx.z == 0) {
        if ((int)blockIdx.x < nbx1 && (int)blockIdx.y < nby1)
            gemm_dev<K1, LDA1, OUTN1, BM1, BN1, BO1>(A1, Wt1, b1, Cf1, Cb1, lds,
                                                     blockIdx.x, blockIdx.y);
    } else {
        if ((int)blockIdx.x < nbx2 && (int)blockIdx.y < nby2)
            gemm_dev<K2, LDA2, OUTN2, BM2, BN2, BO2>(A2, Wt2, b2, Cf2, Cb2, lds,
                                                     blockIdx.x, blockIdx.y);
    }
}

// ---------------------------------------------------------------------------
// Merged node scores for BOTH paths in one launch (grid split).
// ---------------------------------------------------------------------------
template<int F>
__device__ inline void score_one(
    const short* __restrict__ proj_b,
    const float* __restrict__ a_src, const float* __restrict__ a_trg,
    float* __restrict__ ssrc, float* __restrict__ strg, int t)
{
    int n = t >> 2, h = t & 3;
    const int4* p = (const int4*)(proj_b + (size_t)n * (4 * F) + h * F);
    const float* as = a_src + h * F;
    const float* at = a_trg + h * F;
    float ss = 0.f, st = 0.f;
    #pragma unroll
    for (int c = 0; c < F / 8; ++c) {
        int4 v = p[c];
        int u[4] = { v.x, v.y, v.z, v.w };
        #pragma unroll
        for (int q = 0; q < 4; ++q) {
            float x0 = blo(u[q]), x1 = bhi(u[q]);
            ss += x0 * as[c * 8 + 2 * q] + x1 * as[c * 8 + 2 * q + 1];
            st += x0 * at[c * 8 + 2 * q] + x1 * at[c * 8 + 2 * q + 1];
        }
    }
    ssrc[t] = ss;
    strg[t] = st;
}

__global__ __launch_bounds__(256) void scores_both(
    const short* __restrict__ projG,
    const float* __restrict__ agsG, const float* __restrict__ agtG,
    float* __restrict__ ssrcG, float* __restrict__ strgG,
    const short* __restrict__ projC,
    const float* __restrict__ acsC, const float* __restrict__ actC,
    float* __restrict__ ssrcC, float* __restrict__ strgC)
{
    int t = blockIdx.x * 256 + threadIdx.x;
    if (t < NN * HH) score_one<64>(projG, agsG, agtG, ssrcG, strgG, t);
    else             score_one<96>(projC, acsC, actC, ssrcC, strgC, t - NN * HH);
}

// ---------------------------------------------------------------------------
// Fused prologue: concat (0..5119), 6 weight transposes (5120..5983),
// zero deg arrays (5984..6047).
// ---------------------------------------------------------------------------
__global__ __launch_bounds__(256) void prep_kernel(
    const float* __restrict__ rna, const float* __restrict__ prot,
    short* __restrict__ cb,
    const float* W0, const float* W1, const float* W2,
    const float* W3, const float* W4, const float* W5,
    short* T0, short* T1, short* T2, short* T3, short* T4, short* T5,
    int4* __restrict__ zero_p)
{
    const int bid = blockIdx.x;
    if (bid < 5120) {
        int t = bid * 256 + threadIdx.x;
        int n = t / 40, j = (t - n * 40) * 4;
        float4 v = (j < 128) ? *(const float4*)(rna  + (size_t)n * 128 + j)
                             : *(const float4*)(prot + (size_t)n * 32 + (j - 128));
        short4 o = { f2b(v.x), f2b(v.y), f2b(v.z), f2b(v.w) };
        *(short4*)(cb + (size_t)n * 160 + j) = o;
    } else if (bid < 5984) {
        int idx = bid - 5120;
        int wsel = idx / 144, sub = idx - wsel * 144;
        int K, N; const float* W; short* T;
        switch (wsel) {
            case 0: K = 128; N =  64; W = W0; T = T0; break;
            case 1: K =  64; N = 256; W = W1; T = T1; break;
            case 2: K =  64; N = 128; W = W2; T = T2; break;
            case 3: K = 160; N =  96; W = W3; T = T3; break;
            case 4: K =  96; N = 384; W = W4; T = T4; break;
            default:K =  96; N = 160; W = W5; T = T5; break;
        }
        int t = sub * 256 + threadIdx.x;
        if (t >= K * N) return;
        int n = t / K, k = t - n * K;
        T[t] = f2b(W[(size_t)k * N + n]);
    } else {
        zero_p[(bid - 5984) * 256 + threadIdx.x] = make_int4(0, 0, 0, 0);
    }
}

// ---------------------------------------------------------------------------
// Dual CSR build (trg-CSR for aggregation, src-CSR for cross denominators).
// ---------------------------------------------------------------------------
__global__ __launch_bounds__(256) void hist_dual(const int* __restrict__ ei,
                                                 int* __restrict__ deg_t,
                                                 int* __restrict__ deg_s)
{
    int e = blockIdx.x * 256 + threadIdx.x;
    if (e >= NE) return;
    atomicAdd(&deg_s[ei[e]], 1);
    atomicAdd(&deg_t[ei[NE + e]], 1);
}

__global__ __launch_bounds__(1024) void scan_dual(
    const int* __restrict__ deg_t, int* __restrict__ rowptr_t, int* __restrict__ cursor_t,
    const int* __restrict__ deg_s, int* __restrict__ rowptr_s, int* __restrict__ cursor_s)
{
    const int* deg    = blockIdx.x ? deg_s    : deg_t;
    int*       rowptr = blockIdx.x ? rowptr_s : rowptr_t;
    int*       cursor = blockIdx.x ? cursor_s : cursor_t;
    __shared__ int sums[1024];
    const int t = threadIdx.x;
    const int base = t * 32;
    int local[32];
    int s = 0;
    #pragma unroll
    for (int i = 0; i < 32; ++i) { local[i] = s; s += deg[base + i]; }
    sums[t] = s;
    __syncthreads();
    for (int off = 1; off < 1024; off <<= 1) {
        int v = (t >= off) ? sums[t - off] : 0;
        __syncthreads();
        sums[t] += v;
        __syncthreads();
    }
    const int prev = (t == 0) ? 0 : sums[t - 1];
    #pragma unroll
    for (int i = 0; i < 32; ++i) {
        rowptr[base + i] = prev + local[i];
        cursor[base + i] = prev + local[i];
    }
    if (t == 1023) rowptr[NN] = prev + s;
}

__global__ __launch_bounds__(256) void scatter_dual(
    const int* __restrict__ ei,
    int* __restrict__ cursor_t, int* __restrict__ csr_srcT,
    int* __restrict__ cursor_s, int* __restrict__ csr_trgS)
{
    int e = blockIdx.x * 256 + threadIdx.x;
    if (e >= NE) return;
    int s = ei[e], t = ei[NE + e];
    int st = atomicAdd(&cursor_t[t], 1);
    csr_srcT[st] = s;
    int ss = atomicAdd(&cursor_s[s], 1);
    csr_trgS[ss] = t;
}

// ---------------------------------------------------------------------------
// Cross denominator reciprocals via src-CSR.
// ---------------------------------------------------------------------------
__global__ __launch_bounds__(256) void den_src_kernel(
    const int* __restrict__ rowptr_s, const int* __restrict__ csr_trgS,
    const float* __restrict__ ssrc, const float* __restrict__ strg,
    float* __restrict__ recip)
{
    int n = blockIdx.x * 256 + threadIdx.x;
    if (n >= NN) return;
    const int beg = rowptr_s[n], end = rowptr_s[n + 1];
    const float4 sv = *(const float4*)(ssrc + 4 * (size_t)n);
    float d0 = 0.f, d1 = 0.f, d2 = 0.f, d3 = 0.f;
    for (int sl = beg; sl < end; ++sl) {
        const int t = csr_trgS[sl];
        const float4 tv = *(const float4*)(strg + 4 * (size_t)t);
        d0 += lrexp(sv.x + tv.x); d1 += lrexp(sv.y + tv.y);
        d2 += lrexp(sv.z + tv.z); d3 += lrexp(sv.w + tv.w);
    }
    *(float4*)(recip + 4 * (size_t)n) =
        make_float4(1.f / (d0 + 1e-16f), 1.f / (d1 + 1e-16f),
                    1.f / (d2 + 1e-16f), 1.f / (d3 + 1e-16f));
}

// ---------------------------------------------------------------------------
// Fused softmax+aggregate body (round-9-proven, unroll 2).
// ---------------------------------------------------------------------------
template<int F, bool GROUP_SRC>
__device__ __forceinline__ void agg_body(
    int f2, int node,
    const int* __restrict__ rowptr_t, const int* __restrict__ csr_srcT,
    const float* __restrict__ ssrc, const float* __restrict__ strg,
    const float* __restrict__ recip,
    const short* __restrict__ proj_b,
    const short* __restrict__ x_pb, const float* __restrict__ bias,
    short* __restrict__ aggb)
{
    const int beg = rowptr_t[node], end = rowptr_t[node + 1];
    const float4 stv = *(const float4*)(strg + 4 * (size_t)node);

    float a0 = 0.f, a1 = 0.f;
    float h0l = 0.f, h1l = 0.f, h2l = 0.f, h3l = 0.f;
    float h0h = 0.f, h1h = 0.f, h2h = 0.f, h3h = 0.f;
    float d0 = 0.f, d1 = 0.f, d2 = 0.f, d3 = 0.f;

    #pragma unroll 2
    for (int sl = beg; sl < end; ++sl) {
        const int s = csr_srcT[sl];
        const float4 sv = *(const float4*)(ssrc + 4 * (size_t)s);
        float e0 = lrexp(sv.x + stv.x);
        float e1 = lrexp(sv.y + stv.y);
        float e2 = lrexp(sv.z + stv.z);
        float e3 = lrexp(sv.w + stv.w);
        const short* p = proj_b + (size_t)s * (4 * F) + f2;
        const int u0 = *(const int*)(p);
        const int u1 = *(const int*)(p + F);
        const int u2 = *(const int*)(p + 2 * F);
        const int u3 = *(const int*)(p + 3 * F);
        if constexpr (GROUP_SRC) {
            const float4 rc = *(const float4*)(recip + 4 * (size_t)s);
            e0 *= rc.x; e1 *= rc.y; e2 *= rc.z; e3 *= rc.w;
            a0 += e0 * blo(u0) + e1 * blo(u1) + e2 * blo(u2) + e3 * blo(u3);
            a1 += e0 * bhi(u0) + e1 * bhi(u1) + e2 * bhi(u2) + e3 * bhi(u3);
        } else {
            d0 += e0; d1 += e1; d2 += e2; d3 += e3;
            h0l += e0 * blo(u0); h0h += e0 * bhi(u0);
            h1l += e1 * blo(u1); h1h += e1 * bhi(u1);
            h2l += e2 * blo(u2); h2h += e2 * bhi(u2);
            h3l += e3 * blo(u3); h3h += e3 * bhi(u3);
        }
    }
    if constexpr (!GROUP_SRC) {
        const float r0 = 1.f / (d0 + 1e-16f), r1 = 1.f / (d1 + 1e-16f);
        const float r2 = 1.f / (d2 + 1e-16f), r3 = 1.f / (d3 + 1e-16f);
        a0 = h0l * r0 + h1l * r1 + h2l * r2 + h3l * r3;
        a1 = h0h * r0 + h1h * r1 + h2h * r2 + h3h * r3;
    }
    const int o = node * F + f2;
    const int ux = *(const int*)(x_pb + o);
    const float v0 = a0 * 0.25f + blo(ux) + bias[f2];
    const float v1 = a1 * 0.25f + bhi(ux) + bias[f2 + 1];
    *(int*)(aggb + o) = (f2b(v0) & 0xffff) | ((int)f2b(v1) << 16);
}

// ---------------------------------------------------------------------------
// BOTH aggregates in one launch, block-granular dispatch (round-12-proven:
// best measured config, 41.5us). Blocks [0,2731) GAT (32 lanes x 12 nodes),
// blocks [2731,6827) cross (48 lanes x 8 nodes).
// ---------------------------------------------------------------------------
#define GAT_BLKS 2731
__global__ __launch_bounds__(384) void aggregate_mega(
    const int* __restrict__ rowptr_t, const int* __restrict__ csr_srcT,
    const float* __restrict__ ssrcG, const float* __restrict__ strgG,
    const float* __restrict__ ssrcC, const float* __restrict__ strgC,
    const float* __restrict__ recip,
    const short* __restrict__ projG, const short* __restrict__ projC,
    const short* __restrict__ xG, const short* __restrict__ xC,
    const float* __restrict__ biasG, const float* __restrict__ biasC,
    short* __restrict__ aggG, short* __restrict__ aggC)
{
    const int bid = blockIdx.x;
    const int tid = threadIdx.x;
    if (bid < GAT_BLKS) {
        const int node = bid * 12 + tid / 32;
        const int f2   = (tid & 31) * 2;
        if (node >= NN) return;
        agg_body<64, false>(f2, node, rowptr_t, csr_srcT, ssrcG, strgG,
                            nullptr, projG, xG, biasG, aggG);
    } else {
        const int b    = bid - GAT_BLKS;
        const int node = b * 8 + tid / 48;
        const int f2   = (tid % 48) * 2;
        agg_body<96, true>(f2, node, rowptr_t, csr_srcT, ssrcC, strgC,
                           recip, projC, xC, biasC, aggC);
    }
}

// ---------------------------------------------------------------------------
extern "C" void kernel_launch(void* const* d_in, const int* in_sizes, int n_in,
                              void* d_out, int out_size, void* d_ws, size_t ws_size,
                              hipStream_t stream)
{
    const float* rna   = (const float*)d_in[0];    // [N,128]
    const float* prot  = (const float*)d_in[1];    // [N,32]
    const int*   ei    = (const int*)  d_in[2];    // [2,E]
    const float* Wgp   = (const float*)d_in[3];    // [128,64]
    const float* bgp   = (const float*)d_in[4];
    const float* Wgr   = (const float*)d_in[5];    // [64,128]
    const float* bgr   = (const float*)d_in[6];
    const float* Wg    = (const float*)d_in[7];    // [64,256]
    const float* ags   = (const float*)d_in[8];    // [4,64]
    const float* agt   = (const float*)d_in[9];
    const float* bg    = (const float*)d_in[10];   // [64]
    const float* Wcp   = (const float*)d_in[11];   // [160,96]
    const float* bcp   = (const float*)d_in[12];
    const float* Wcr   = (const float*)d_in[13];   // [96,160]
    const float* bcr   = (const float*)d_in[14];
    const float* Wc    = (const float*)d_in[15];   // [96,384]
    const float* acs   = (const float*)d_in[16];   // [4,96]
    const float* act   = (const float*)d_in[17];
    const float* bc    = (const float*)d_in[18];   // [96]

    float* out_gat   = (float*)d_out;              // [N,128]
    float* out_cross = out_gat + (size_t)NN * 128; // [N,160]

    // ---- workspace layout (~79 MB) ----
    float* ssrcG  = (float*)d_ws;                  // N*4
    float* strgG  = ssrcG + (size_t)NN * 4;        // N*4
    float* ssrcC  = strgG + (size_t)NN * 4;        // N*4
    float* strgC  = ssrcC + (size_t)NN * 4;        // N*4
    float* recip  = strgC + (size_t)NN * 4;        // N*4
    short* projG  = (short*)(recip + (size_t)NN * 4); // N*256 bf16
    short* projC  = projG + (size_t)NN * 256;      // N*384 bf16
    short* cb     = projC + (size_t)NN * 384;      // N*160 bf16
    short* x_pG   = cb    + (size_t)NN * 160;      // N*64 bf16
    short* x_pC   = x_pG  + (size_t)NN * 64;       // N*96 bf16
    short* aggG   = x_pC  + (size_t)NN * 96;       // N*64 bf16
    short* aggC   = aggG  + (size_t)NN * 64;       // N*96 bf16
    short* wt_gp  = aggC  + (size_t)NN * 96;       // [64,128]
    short* wt_g   = wt_gp + 128 * 64;              // [256,64]
    short* wt_gr  = wt_g  + 64 * 256;              // [128,64]
    short* wt_cp  = wt_gr + 64 * 128;              // [96,160]
    short* wt_c   = wt_cp + 160 * 96;              // [384,96]
    short* wt_cr  = wt_c  + 96 * 384;              // [160,96]
    int*   deg_t  = (int*)(wt_cr + 96 * 160);      // N
    int*   deg_s  = deg_t  + NN;                   // N
    int*   cursor_t = deg_s  + NN;                 // N
    int*   cursor_s = cursor_t + NN;               // N
    int*   rowptr_t = cursor_s + NN;               // N+1
    int*   rowptr_s = rowptr_t + NN + 1;           // N+1
    int*   csr_srcT = rowptr_s + NN + 1;           // E
    int*   csr_trgS = csr_srcT + NE;               // E

    // ---- prologue + CSR build ----
    prep_kernel<<<6048, 256, 0, stream>>>(rna, prot, cb,
                                          Wgp, Wg, Wgr, Wcp, Wc, Wcr,
                                          wt_gp, wt_g, wt_gr, wt_cp, wt_c, wt_cr,
                                          (int4*)deg_t);
    hist_dual<<<NE / 256, 256, 0, stream>>>(ei, deg_t, deg_s);
    scan_dual<<<2, 1024, 0, stream>>>(deg_t, rowptr_t, cursor_t, deg_s, rowptr_s, cursor_s);
    scatter_dual<<<NE / 256, 256, 0, stream>>>(ei, cursor_t, csr_srcT, cursor_s, csr_trgS);

    // ---- stage-1 projection GEMMs (both paths, one launch) ----
    dual_gemm<128, 160,  64, 32,  64, true,
              160, 160,  96, 64,  96, true><<<dim3(1024, 1, 2), 256, 0, stream>>>(
        cb, wt_gp, bgp, nullptr, x_pG, 1024, 1,
        cb, wt_cp, bcp, nullptr, x_pC,  512, 1);

    // ---- stage-2 projection GEMMs (both paths, one launch) ----
    dual_gemm< 64,  64, 256, 64, 128, true,
               96,  96, 384, 64, 128, true><<<dim3(512, 3, 2), 256, 0, stream>>>(
        x_pG, wt_g, nullptr, nullptr, projG, 512, 2,
        x_pC, wt_c, nullptr, nullptr, projC, 512, 3);

    // ---- scores (merged), cross denominators ----
    scores_both<<<(2 * NN * HH) / 256, 256, 0, stream>>>(
        projG, ags, agt, ssrcG, strgG, projC, acs, act, ssrcC, strgC);
    den_src_kernel<<<NN / 256, 256, 0, stream>>>(rowptr_s, csr_trgS, ssrcC, strgC, recip);

    // ---- both aggregates, one launch (round-12 block-granular split) ----
    aggregate_mega<<<GAT_BLKS + NN / 8, 384, 0, stream>>>(
        rowptr_t, csr_srcT, ssrcG, strgG, ssrcC, strgC, recip,
        projG, projC, x_pG, x_pC, bg, bc, aggG, aggC);

    // ---- reprojection GEMMs (both paths, one launch) ----
    dual_gemm< 64,  64, 128, 64,  64, false,
               96,  96, 160, 64, 160, false><<<dim3(512, 2, 2), 256, 0, stream>>>(
        aggG, wt_gr, bgr, out_gat,   nullptr, 512, 2,
        aggC, wt_cr, bcr, out_cross, nullptr, 512, 1);
}